// Round 7
// baseline (296.023 us; speedup 1.0000x reference)
//
#include <hip/hip_runtime.h>
#include <hip/hip_bf16.h>

#define N_NODES 50000
#define N_EDGES 800000
#define DD 64
#define RPB 32
#define GBLOCKS ((N_NODES + RPB - 1) / RPB)       // 1563 (gather, 256 thr)
#define MBLOCKS ((N_NODES + 63) / 64)             // 782
#define NBUCKET ((N_NODES + 63) / 64)             // 782
#define SCAN_BLOCKS ((N_NODES + 255) / 256)       // 196
#define EDGE_BLOCKS (N_EDGES / 256)               // 3125
#define FA2_EPB 4096
#define FA2_BLOCKS ((N_EDGES + FA2_EPB - 1) / FA2_EPB)  // 196
#define BN_EPS 1e-5f

// R24: gather block halved to 256 threads / RPB=32 (grid 1563). Wave-internal
// lane geometry IDENTICAL (rs=lane>>3, ch=lane&7, 8 rows x 8 chunks per wave,
// per-row stream ownership). Mechanism: finer scheduling quanta (less
// per-block tail behind the __syncthreads), staging halves before the
// barrier, LDS 28.5 -> 14 KB. R23 post-mortem: index-chain fix gave only
// -3.6 us => gather is xb-latency-bound at the ~4-deep pipeline the VGPR=64
// pin allows; granularity is the remaining safe lever.
//
// R23: srt staged in LDS as byte offsets (kept). R17: fillA LDS counting
// sort (kept). CLOSED FAMILIES: k-tiling the VALU GEMMs (R19/R21 detonated
// the allocator: 256 VGPR + 475-749 MB scratch); deeper reg pipelines /
// launch_bounds waves-arg (R18/R19); coop fusion (R20, 4x). wcol[64]
// epilogue at the VGPR=64 pin is the proven form.
//
// ws layout (fp32 words), ~11.7 MB:
//   [0..127] sumsA  [128..255] sumsB  [256..] flags (isf, i64)
//   cnt@512[50048], off[50064], bcur[782*16 line-padded], bsum[256],
//   tmp32[800000 u32], srt[800000 u16], xb[3.2M bf16]
// Words [0 .. 50560) zeroed by hipMemsetAsync before initcast (sums + flags + cnt).
// d_out (fp32): O1 = h1 (fp32 self-term source), O2 = hpre scratch -> h2.

__device__ __forceinline__ float bf2f(unsigned short b) {
    return __uint_as_float(((unsigned)b) << 16);
}
__device__ __forceinline__ float loadF(const void* p, int i, int isf) {
    return isf ? ((const float*)p)[i] : bf2f(((const unsigned short*)p)[i]);
}
template<bool ISF>
__device__ __forceinline__ float4 ld4(const void* p, int i) {
    if (ISF) return *reinterpret_cast<const float4*>((const float*)p + i);
    ushort4 u = *reinterpret_cast<const ushort4*>((const unsigned short*)p + i);
    return make_float4(bf2f(u.x), bf2f(u.y), bf2f(u.z), bf2f(u.w));
}
// accumulate 8 bf16 (packed in uint4) into two float4s
__device__ __forceinline__ void acc8(float4& a, float4& b, uint4 u) {
    a.x += __uint_as_float(u.x << 16);
    a.y += __uint_as_float(u.x & 0xFFFF0000u);
    a.z += __uint_as_float(u.y << 16);
    a.w += __uint_as_float(u.y & 0xFFFF0000u);
    b.x += __uint_as_float(u.z << 16);
    b.y += __uint_as_float(u.z & 0xFFFF0000u);
    b.z += __uint_as_float(u.w << 16);
    b.w += __uint_as_float(u.w & 0xFFFF0000u);
}

// Merged: sniff (local per block), node-histogram (1 edge/thread), cast x -> bf16 xb.
// cnt/sums pre-zeroed by hipMemsetAsync. Grid = 3125 (one thread per edge).
__global__ __launch_bounds__(256) void initcast_kernel(
    const void* __restrict__ x, const int* __restrict__ ei,
    int* __restrict__ flags, int* __restrict__ cnt,
    unsigned short* __restrict__ xb)
{
    __shared__ int cntF, cntI;
    int t = threadIdx.x;
    if (t == 0) { cntF = 0; cntI = 0; }
    __syncthreads();
    unsigned short wd = ((const unsigned short*)x)[2 * t];
    int e = (wd >> 7) & 0xFF;
    if (e >= 0x70 && e <= 0x8F) atomicAdd(&cntF, 1);        // bf16-plausible exponent
    if (t < 128 && ei[2 * t + 1] == 0) atomicAdd(&cntI, 1); // int64 high words are 0
    __syncthreads();
    int isf = (cntF < 128) ? 1 : 0;
    int i64 = (cntI > 64) ? 1 : 0;

    int gid = blockIdx.x * 256 + t;
    if (blockIdx.x == 0 && t == 0) {
        flags[0] = isf;
        flags[1] = i64;
    }

    // histogram: this thread's edge
    {
        int d = i64 ? ei[2 * N_EDGES + 2 * gid] : ei[N_EDGES + gid];
        atomicAdd(cnt + d, 1);
    }

    // cast: 8 elems/thread for gid < 400000
    int i = gid * 8;
    if (i < N_NODES * DD) {
        if (isf) {
            float4 a = *reinterpret_cast<const float4*>((const float*)x + i);
            float4 b = *reinterpret_cast<const float4*>((const float*)x + i + 4);
            ushort4 o0, o1;
            o0.x = __bfloat16_as_ushort(__float2bfloat16(a.x));
            o0.y = __bfloat16_as_ushort(__float2bfloat16(a.y));
            o0.z = __bfloat16_as_ushort(__float2bfloat16(a.z));
            o0.w = __bfloat16_as_ushort(__float2bfloat16(a.w));
            o1.x = __bfloat16_as_ushort(__float2bfloat16(b.x));
            o1.y = __bfloat16_as_ushort(__float2bfloat16(b.y));
            o1.z = __bfloat16_as_ushort(__float2bfloat16(b.z));
            o1.w = __bfloat16_as_ushort(__float2bfloat16(b.w));
            *reinterpret_cast<ushort4*>(xb + i) = o0;
            *reinterpret_cast<ushort4*>(xb + i + 4) = o1;
        } else {
            *reinterpret_cast<uint4*>(xb + i) =
                *reinterpret_cast<const uint4*>((const unsigned short*)x + i);
        }
    }
}

// block-local exclusive scan into off + per-block sums
__global__ __launch_bounds__(256) void scanA_kernel(const int* __restrict__ cnt,
                                                    int* __restrict__ off,
                                                    int* __restrict__ bsum) {
    __shared__ int tmp[256];
    int t = threadIdx.x;
    int i = blockIdx.x * 256 + t;
    int v = (i < N_NODES) ? cnt[i] : 0;
    tmp[t] = v;
    __syncthreads();
    #pragma unroll
    for (int d = 1; d < 256; d <<= 1) {
        int u = (t >= d) ? tmp[t - d] : 0;
        __syncthreads();
        tmp[t] += u;
        __syncthreads();
    }
    if (i < N_NODES) off[i] = tmp[t] - v;
    if (t == 255) bsum[blockIdx.x] = tmp[255];
}

// scanB folded in: every block redundantly scans bsum[196] in LDS, then adds its base.
// Also seeds bucket cursors (bcur, line-padded stride 16) and off[N_NODES].
__global__ __launch_bounds__(256) void scanC_kernel(const int* __restrict__ bsum,
                                                    int* __restrict__ off,
                                                    int* __restrict__ bcur) {
    __shared__ int tmp[256];
    int t = threadIdx.x;
    int v = (t < SCAN_BLOCKS) ? bsum[t] : 0;
    tmp[t] = v;
    __syncthreads();
    #pragma unroll
    for (int d = 1; d < 256; d <<= 1) {
        int u = (t >= d) ? tmp[t - d] : 0;
        __syncthreads();
        tmp[t] += u;
        __syncthreads();
    }
    int base = (blockIdx.x == 0) ? 0 : tmp[blockIdx.x - 1];
    int i = blockIdx.x * 256 + t;
    if (i < N_NODES) {
        int o = off[i] + base;
        off[i] = o;
        if ((i & 63) == 0) bcur[(i >> 6) * 16] = o;
    }
    if (blockIdx.x == SCAN_BLOCKS - 1 && t == 0) off[N_NODES] = tmp[SCAN_BLOCKS - 1];
}

// Pass A (R17): block-local LDS counting sort by bucket (bucket = dst>>6), then
// burst write each bucket's run into its reserved span of tmp32. One global
// atomic per (block,bucket) instead of one per edge; writes are coalesced runs
// (avg 5.2 entries) so each 64B line is produced by ~2-3 blocks, not ~8 XCDs.
// Pack: s(16) | (d&63)<<16 | bucket<<22 — bucket<782 fits 10 bits, never all-ones.
__global__ __launch_bounds__(1024) void fillA_kernel(const int* __restrict__ ei,
                                                     int* __restrict__ bcur,
                                                     unsigned int* __restrict__ tmp,
                                                     const int* __restrict__ flags) {
    __shared__ int sHist[1024];            // per-bucket count (782 used)
    __shared__ int sStart[1024];           // exclusive scan (local sorted offset)
    __shared__ int sCur[1024];             // scatter cursors
    __shared__ int sBase[1024];            // reserved global base per bucket
    __shared__ int sWS[16];                // per-wave scan sums
    __shared__ unsigned int sorted[FA2_EPB];

    int t = threadIdx.x;
    int lane = t & 63, wid = t >> 6;
    int i64 = flags[1];

    sHist[t] = 0;
    __syncthreads();

    unsigned int vals[4];
    int e0 = blockIdx.x * FA2_EPB + t;
    #pragma unroll
    for (int j = 0; j < 4; ++j) {
        int e = e0 + j * 1024;
        vals[j] = 0xFFFFFFFFu;
        if (e < N_EDGES) {
            int s, d;
            if (i64) { s = ei[2 * e]; d = ei[2 * N_EDGES + 2 * e]; }
            else     { s = ei[e];     d = ei[N_EDGES + e]; }
            int b = d >> 6;
            vals[j] = (unsigned)s | ((unsigned)(d & 63) << 16) | ((unsigned)b << 22);
            atomicAdd(&sHist[b], 1);
        }
    }
    __syncthreads();

    // inclusive scan of sHist[0..1023]: shfl within wave, then scan 16 wave sums
    int h = sHist[t];
    int x = h;
    #pragma unroll
    for (int dd = 1; dd < 64; dd <<= 1) {
        int y = __shfl_up(x, dd, 64);
        if (lane >= dd) x += y;
    }
    if (lane == 63) sWS[wid] = x;
    __syncthreads();
    if (wid == 0) {
        int v = (lane < 16) ? sWS[lane] : 0;
        #pragma unroll
        for (int dd = 1; dd < 16; dd <<= 1) {
            int y = __shfl_up(v, dd, 64);
            if (lane >= dd) v += y;
        }
        if (lane < 16) sWS[lane] = v;
    }
    __syncthreads();
    int base = (wid == 0) ? 0 : sWS[wid - 1];
    int incl = x + base;
    int lst = incl - h;
    sStart[t] = lst;
    sCur[t] = lst;
    if (t < NBUCKET && h > 0) sBase[t] = atomicAdd(bcur + t * 16, h);
    int total = sWS[15];
    __syncthreads();

    // LDS scatter: sort this block's edges by bucket
    #pragma unroll
    for (int j = 0; j < 4; ++j) {
        unsigned int v = vals[j];
        if (v != 0xFFFFFFFFu) {
            int b = v >> 22;
            int p = atomicAdd(&sCur[b], 1);
            sorted[p] = v;
        }
    }
    __syncthreads();

    // burst write-out: consecutive i in the same bucket -> consecutive global addrs
    for (int i = t; i < total; i += 1024) {
        unsigned int v = sorted[i];
        int b = v >> 22;
        tmp[sBase[b] + (i - sStart[b])] = v & 0x3FFFFFu;  // strip bucket bits for fillB
    }
}

// Pass B: one block per bucket; exact per-node placement via LDS counters.
__global__ __launch_bounds__(256) void fillB_kernel(const int* __restrict__ off,
                                                    const unsigned int* __restrict__ tmp,
                                                    unsigned short* __restrict__ srt) {
    __shared__ int cur64[64];
    int b = blockIdx.x;
    int t = threadIdx.x;
    if (t < 64) {
        int idx = b * 64 + t;
        cur64[t] = (idx < N_NODES) ? off[idx] : N_EDGES;
    }
    __syncthreads();
    int start = off[b * 64];
    int endn  = (b + 1) * 64; if (endn > N_NODES) endn = N_NODES;
    int end   = off[endn];
    for (int i = start + t; i < end; i += 256) {
        unsigned v = tmp[i];
        int pos = atomicAdd(&cur64[v >> 16], 1);
        srt[pos] = (unsigned short)(v & 0xFFFFu);
    }
}

// Fused: CSR bf16-gather -> LDS -> GEMM (W1,b1) -> hpre + BN sums.
// R24: 256 threads = 4 waves x 8 row-slots, RPB=32, grid 1563. Wave-internal
// geometry IDENTICAL to the R13 local optimum: lane (rs = lane>>3, ch = lane&7)
// owns the FULL neighbor stream of row (w*8+rs), chunk ch. R23: block's srt
// segment staged in LDS as byte offsets (n<<7). 16-deep gather source
// (compiler serializes safely at VGPR=64). wcol[64] epilogue is the proven
// form (k-tiling detonates: R19/R21). DO NOT alter intra-wave lane geometry.
__global__ __launch_bounds__(256) void gather_gemm_stats_kernel(
    const unsigned short* __restrict__ xb, const void* __restrict__ self_src, int force_f32,
    const int* __restrict__ off, const unsigned short* __restrict__ srt,
    const void* __restrict__ W, const void* __restrict__ bias,
    float* __restrict__ out_, float* __restrict__ sums, const int* __restrict__ flags)
{
    __shared__ float sIn[RPB][DD];            // 8 KB agg tile
    __shared__ float r1[4][DD], r2[4][DD];    // 2 KB stats
    __shared__ unsigned sOff[1024];           // 4 KB staged neighbor byte-offsets
    int tid = threadIdx.x;
    int lane = tid & 63, w = tid >> 6;        // wave 0..3
    int rs = lane >> 3, ch = lane & 7;
    int row0 = blockIdx.x * RPB;
    int isf = force_f32 ? 1 : flags[0];

    // cooperative stage: block's contiguous srt range -> LDS byte offsets.
    // count = Poisson(512); 1024 capacity = 2x mean (same ratio as R23's 2048).
    int rEnd = row0 + RPB; if (rEnd > N_NODES) rEnd = N_NODES;
    int blkStart = off[row0];
    int blkCount = off[rEnd] - blkStart;
    for (int i = tid; i < blkCount; i += 256)
        sOff[i] = ((unsigned)srt[blkStart + i]) << 7;
    __syncthreads();

    int lr = w * 8 + rs;
    int r = row0 + lr;
    float4 a  = make_float4(0.f, 0.f, 0.f, 0.f);
    float4 b  = make_float4(0.f, 0.f, 0.f, 0.f);
    float4 a2 = make_float4(0.f, 0.f, 0.f, 0.f);
    float4 b2 = make_float4(0.f, 0.f, 0.f, 0.f);
    if (r < N_NODES) {
        a = isf ? ld4<true>(self_src, r * DD + 8 * ch)
                : ld4<false>(self_src, r * DD + 8 * ch);
        b = isf ? ld4<true>(self_src, r * DD + 8 * ch + 4)
                : ld4<false>(self_src, r * DD + 8 * ch + 4);
        int k0 = off[r] - blkStart, k1 = off[r + 1] - blkStart;
        const char* xbc = (const char*)xb + 16 * ch;  // lane-constant chunk base
        int k = k0;
        for (; k + 16 <= k1; k += 16) {       // 16-deep pipelined neighbor loads
            unsigned o0  = sOff[k],      o1  = sOff[k + 1],  o2  = sOff[k + 2],  o3  = sOff[k + 3];
            unsigned o4  = sOff[k + 4],  o5  = sOff[k + 5],  o6  = sOff[k + 6],  o7  = sOff[k + 7];
            unsigned o8  = sOff[k + 8],  o9  = sOff[k + 9],  o10 = sOff[k + 10], o11 = sOff[k + 11];
            unsigned o12 = sOff[k + 12], o13 = sOff[k + 13], o14 = sOff[k + 14], o15 = sOff[k + 15];
            uint4 u0  = *reinterpret_cast<const uint4*>(xbc + o0);
            uint4 u1  = *reinterpret_cast<const uint4*>(xbc + o1);
            uint4 u2  = *reinterpret_cast<const uint4*>(xbc + o2);
            uint4 u3  = *reinterpret_cast<const uint4*>(xbc + o3);
            uint4 u4  = *reinterpret_cast<const uint4*>(xbc + o4);
            uint4 u5  = *reinterpret_cast<const uint4*>(xbc + o5);
            uint4 u6  = *reinterpret_cast<const uint4*>(xbc + o6);
            uint4 u7  = *reinterpret_cast<const uint4*>(xbc + o7);
            uint4 u8  = *reinterpret_cast<const uint4*>(xbc + o8);
            uint4 u9  = *reinterpret_cast<const uint4*>(xbc + o9);
            uint4 u10 = *reinterpret_cast<const uint4*>(xbc + o10);
            uint4 u11 = *reinterpret_cast<const uint4*>(xbc + o11);
            uint4 u12 = *reinterpret_cast<const uint4*>(xbc + o12);
            uint4 u13 = *reinterpret_cast<const uint4*>(xbc + o13);
            uint4 u14 = *reinterpret_cast<const uint4*>(xbc + o14);
            uint4 u15 = *reinterpret_cast<const uint4*>(xbc + o15);
            acc8(a, b, u0);   acc8(a2, b2, u1);
            acc8(a, b, u2);   acc8(a2, b2, u3);
            acc8(a, b, u4);   acc8(a2, b2, u5);
            acc8(a, b, u6);   acc8(a2, b2, u7);
            acc8(a, b, u8);   acc8(a2, b2, u9);
            acc8(a, b, u10);  acc8(a2, b2, u11);
            acc8(a, b, u12);  acc8(a2, b2, u13);
            acc8(a, b, u14);  acc8(a2, b2, u15);
        }
        for (; k + 8 <= k1; k += 8) {         // 8-deep tail
            unsigned o0 = sOff[k],     o1 = sOff[k + 1], o2 = sOff[k + 2], o3 = sOff[k + 3];
            unsigned o4 = sOff[k + 4], o5 = sOff[k + 5], o6 = sOff[k + 6], o7 = sOff[k + 7];
            uint4 u0 = *reinterpret_cast<const uint4*>(xbc + o0);
            uint4 u1 = *reinterpret_cast<const uint4*>(xbc + o1);
            uint4 u2 = *reinterpret_cast<const uint4*>(xbc + o2);
            uint4 u3 = *reinterpret_cast<const uint4*>(xbc + o3);
            uint4 u4 = *reinterpret_cast<const uint4*>(xbc + o4);
            uint4 u5 = *reinterpret_cast<const uint4*>(xbc + o5);
            uint4 u6 = *reinterpret_cast<const uint4*>(xbc + o6);
            uint4 u7 = *reinterpret_cast<const uint4*>(xbc + o7);
            acc8(a, b, u0);
            acc8(a2, b2, u1);
            acc8(a, b, u2);
            acc8(a2, b2, u3);
            acc8(a, b, u4);
            acc8(a2, b2, u5);
            acc8(a, b, u6);
            acc8(a2, b2, u7);
        }
        for (; k + 2 <= k1; k += 2) {
            unsigned o0 = sOff[k], o1 = sOff[k + 1];
            uint4 u0 = *reinterpret_cast<const uint4*>(xbc + o0);
            uint4 u1 = *reinterpret_cast<const uint4*>(xbc + o1);
            acc8(a, b, u0);
            acc8(a2, b2, u1);
        }
        if (k < k1) {
            acc8(a, b, *reinterpret_cast<const uint4*>(xbc + sOff[k]));
        }
        a.x += a2.x; a.y += a2.y; a.z += a2.z; a.w += a2.w;
        b.x += b2.x; b.y += b2.y; b.z += b2.z; b.w += b2.w;
    }
    *reinterpret_cast<float4*>(&sIn[lr][8 * ch]) = a;
    *reinterpret_cast<float4*>(&sIn[lr][8 * ch + 4]) = b;
    __syncthreads();

    float wcol[DD];                           // W[:,c], c = lane
    #pragma unroll
    for (int k = 0; k < DD; ++k) wcol[k] = loadF(W, k * DD + lane, isf);
    float bv = loadF(bias, lane, isf);

    float s1 = 0.f, s2 = 0.f;
    #pragma unroll 4
    for (int j = 0; j < 8; ++j) {
        int jr = w * 8 + j;
        float c0 = 0.f, c1 = 0.f, c2 = 0.f, c3 = 0.f;
        #pragma unroll
        for (int k = 0; k < DD; k += 4) {
            float4 aa = *reinterpret_cast<const float4*>(&sIn[jr][k]);  // wave-uniform broadcast
            c0 += aa.x * wcol[k];
            c1 += aa.y * wcol[k + 1];
            c2 += aa.z * wcol[k + 2];
            c3 += aa.w * wcol[k + 3];
        }
        float acc = bv + ((c0 + c1) + (c2 + c3));
        int rr = row0 + jr;
        if (rr < N_NODES) {
            out_[rr * DD + lane] = acc;
            s1 += acc;
            s2 += acc * acc;
        }
    }
    r1[w][lane] = s1; r2[w][lane] = s2;
    __syncthreads();
    if (w == 0) {
        float t1 = 0.f, t2 = 0.f;
        #pragma unroll
        for (int q = 0; q < 4; ++q) { t1 += r1[q][lane]; t2 += r2[q][lane]; }
        atomicAdd(&sums[lane], t1);
        atomicAdd(&sums[64 + lane], t2);
    }
}

// h = relu(hpre*scale+shift); out = relu(h @ W2 + b2) -> fp32 (+ optional bf16 shadow).
// BN scale/shift computed inline from sums. In-place safe (LDS staged).
// wcol[64] form — proven; k-tiling detonates the allocator (R21).
__global__ __launch_bounds__(256) void mlp2_kernel(
    const float* __restrict__ in_, const float* __restrict__ sums,
    const void* __restrict__ gma, const void* __restrict__ beta,
    const void* __restrict__ W, const void* __restrict__ bias,
    float* __restrict__ oF, unsigned short* obf, const int* __restrict__ flags)
{
    __shared__ float sIn[64][DD];
    __shared__ float sScale[DD], sShift[DD];
    int isf = flags[0];
    int tid = threadIdx.x;
    int c = tid & 63, g = tid >> 6;
    int row0 = blockIdx.x * 64;

    if (tid < 64) {
        float S1 = sums[tid];
        float S2 = sums[64 + tid];
        float mean = S1 * (1.0f / N_NODES);
        float var  = S2 * (1.0f / N_NODES) - mean * mean;
        float scale = rsqrtf(var + BN_EPS) * loadF(gma, tid, isf);
        sScale[tid] = scale;
        sShift[tid] = loadF(beta, tid, isf) - mean * scale;
    }
    __syncthreads();

    #pragma unroll
    for (int j = 0; j < 4; ++j) {
        int lr = (tid >> 4) + 16 * j;
        int cc = (tid & 15) << 2;
        int r = row0 + lr;
        float4 v = make_float4(0.f, 0.f, 0.f, 0.f);
        if (r < N_NODES) {
            v = *reinterpret_cast<const float4*>(in_ + r * DD + cc);
            float4 sc = *reinterpret_cast<const float4*>(&sScale[cc]);
            float4 sh = *reinterpret_cast<const float4*>(&sShift[cc]);
            v.x = fmaxf(v.x * sc.x + sh.x, 0.f);
            v.y = fmaxf(v.y * sc.y + sh.y, 0.f);
            v.z = fmaxf(v.z * sc.z + sh.z, 0.f);
            v.w = fmaxf(v.w * sc.w + sh.w, 0.f);
        }
        *reinterpret_cast<float4*>(&sIn[lr][cc]) = v;
    }
    __syncthreads();

    float wcol[DD];
    #pragma unroll
    for (int k = 0; k < DD; ++k) wcol[k] = loadF(W, k * DD + c, isf);
    float bv = loadF(bias, c, isf);

    #pragma unroll 4
    for (int j = 0; j < 16; ++j) {
        int lr = g * 16 + j;
        float a0 = 0.f, a1 = 0.f, a2 = 0.f, a3 = 0.f;
        #pragma unroll
        for (int k = 0; k < DD; k += 4) {
            float4 a = *reinterpret_cast<const float4*>(&sIn[lr][k]);
            a0 += a.x * wcol[k];
            a1 += a.y * wcol[k + 1];
            a2 += a.z * wcol[k + 2];
            a3 += a.w * wcol[k + 3];
        }
        float acc = fmaxf(bv + ((a0 + a1) + (a2 + a3)), 0.f);
        int r = row0 + lr;
        if (r < N_NODES) {
            oF[r * DD + c] = acc;
            if (obf) obf[r * DD + c] = __bfloat16_as_ushort(__float2bfloat16(acc));
        }
    }
}

extern "C" void kernel_launch(void* const* d_in, const int* in_sizes, int n_in,
                              void* d_out, int out_size, void* d_ws, size_t ws_size,
                              hipStream_t stream)
{
    (void)in_sizes; (void)n_in; (void)out_size; (void)ws_size;
    const void* x  = d_in[0];
    const int* ei  = (const int*)d_in[1];
    const void* W1_0 = d_in[2];  const void* b1_0 = d_in[3];
    const void* g_0  = d_in[4];  const void* be_0 = d_in[5];
    const void* W2_0 = d_in[6];  const void* b2_0 = d_in[7];
    const void* W1_1 = d_in[8];  const void* b1_1 = d_in[9];
    const void* g_1  = d_in[10]; const void* be_1 = d_in[11];
    const void* W2_1 = d_in[12]; const void* b2_1 = d_in[13];

    float* wsf   = (float*)d_ws;
    float* sumsA = wsf;                            // 128
    float* sumsB = wsf + 128;                      // 128
    int*  flags  = (int*)(wsf + 256);              // 2
    int*  cnt    = (int*)(wsf + 512);              // 50048
    int*  off    = cnt + 50048;                    // 50064
    int*  bcur   = off + 50064;                    // 782*16 = 12512 (line-padded)
    int*  bsum   = bcur + 12512;                   // 256
    unsigned int* tmp32 = (unsigned int*)(bsum + 256) + 48;   // 800000 u32
    unsigned short* srt = (unsigned short*)(tmp32 + 800000);  // 800000 u16
    unsigned short* xb  = srt + 800064;                       // 3.2M bf16, 16B-aligned
    float* O1    = (float*)d_out;                  // h1 (fp32 self-term source)
    float* O2    = O1 + (size_t)N_NODES * DD;      // hpre scratch -> h2

    dim3 blk(256);

    // zero sums/flags/cnt, then CSR build (hist folded into initcast) + bf16 shadow
    hipMemsetAsync(d_ws, 0, (size_t)(512 + 50048) * 4, stream);
    initcast_kernel<<<EDGE_BLOCKS, blk, 0, stream>>>(x, ei, flags, cnt, xb);
    scanA_kernel<<<SCAN_BLOCKS, blk, 0, stream>>>(cnt, off, bsum);
    scanC_kernel<<<SCAN_BLOCKS, blk, 0, stream>>>(bsum, off, bcur);
    fillA_kernel<<<FA2_BLOCKS, 1024, 0, stream>>>(ei, bcur, tmp32, flags);
    fillB_kernel<<<NBUCKET, blk, 0, stream>>>(off, tmp32, srt);

    // ---- layer 1 ----
    gather_gemm_stats_kernel<<<GBLOCKS, 256, 0, stream>>>(xb, x, 0, off, srt, W1_0, b1_0,
                                                          O2, sumsA, flags);
    mlp2_kernel<<<MBLOCKS, blk, 0, stream>>>(O2, sumsA, g_0, be_0, W2_0, b2_0, O1, xb, flags);

    // ---- layer 2 ----
    gather_gemm_stats_kernel<<<GBLOCKS, 256, 0, stream>>>(xb, O1, 1, off, srt, W1_1, b1_1,
                                                          O2, sumsB, flags);
    mlp2_kernel<<<MBLOCKS, blk, 0, stream>>>(O2, sumsB, g_1, be_1, W2_1, b2_1, O2, nullptr, flags);
}

// Round 9
// 262.439 us; speedup vs baseline: 1.1280x; 1.1280x over previous
//
#include <hip/hip_runtime.h>
#include <hip/hip_bf16.h>

#define N_NODES 50000
#define N_EDGES 800000
#define DD 64
#define RPB 64
#define GBLOCKS ((N_NODES + RPB - 1) / RPB)       // 782
#define MBLOCKS ((N_NODES + 63) / 64)             // 782
#define NBUCKET ((N_NODES + 63) / 64)             // 782
#define SCAN_BLOCKS ((N_NODES + 255) / 256)       // 196
#define EDGE_BLOCKS (N_EDGES / 256)               // 3125
#define FA2_EPB 4096
#define FA2_BLOCKS ((N_EDGES + FA2_EPB - 1) / FA2_EPB)  // 196
#define BN_EPS 1e-5f

// R26 = R25 with the compile fix: __builtin_nontemporal_load needs a NATIVE
// vector type (ext_vector_type), not HIP_vector_type<float,4>. nt4 alias
// below is layout-identical to float4; load stays dwordx4.
//
// R25 theory: gather is xb-L2-hit-rate-bound (xb 6.4 MB vs 4 MB/XCD L2);
// our own streams (gather out_ 12.8 MB, mlp2 in/out ~32 MB between the two
// gathers) evict xb. Nontemporal hints on all stream-once traffic keep xb
// resident. No VGPR/unroll/correctness impact.
//
// R23: srt staged in LDS as byte offsets (kept). R17: fillA LDS counting
// sort (kept). CLOSED FAMILIES: k-tiling the VALU GEMMs (R19/R21 detonated
// the allocator: 256 VGPR + 475-749 MB scratch); deeper reg pipelines /
// launch_bounds waves-arg (R18/R19); coop fusion (R20, 4x); block-shape
// halving (R24: 43->58 us). wcol[64] epilogue at the VGPR=64 pin is the
// proven form; 512 thr / RPB=64 is the proven block geometry.
//
// ws layout (fp32 words), ~11.7 MB:
//   [0..127] sumsA  [128..255] sumsB  [256..] flags (isf, i64)
//   cnt@512[50048], off[50064], bcur[782*16 line-padded], bsum[256],
//   tmp32[800000 u32], srt[800000 u16], xb[3.2M bf16]
// Words [0 .. 50560) zeroed by hipMemsetAsync before initcast (sums + flags + cnt).
// d_out (fp32): O1 = h1 (fp32 self-term source), O2 = hpre scratch -> h2.

typedef float nt4 __attribute__((ext_vector_type(4)));  // native vec for nt builtins

__device__ __forceinline__ float bf2f(unsigned short b) {
    return __uint_as_float(((unsigned)b) << 16);
}
__device__ __forceinline__ float loadF(const void* p, int i, int isf) {
    return isf ? ((const float*)p)[i] : bf2f(((const unsigned short*)p)[i]);
}
template<bool ISF>
__device__ __forceinline__ float4 ld4(const void* p, int i) {
    if (ISF) return *reinterpret_cast<const float4*>((const float*)p + i);
    ushort4 u = *reinterpret_cast<const ushort4*>((const unsigned short*)p + i);
    return make_float4(bf2f(u.x), bf2f(u.y), bf2f(u.z), bf2f(u.w));
}
// accumulate 8 bf16 (packed in uint4) into two float4s
__device__ __forceinline__ void acc8(float4& a, float4& b, uint4 u) {
    a.x += __uint_as_float(u.x << 16);
    a.y += __uint_as_float(u.x & 0xFFFF0000u);
    a.z += __uint_as_float(u.y << 16);
    a.w += __uint_as_float(u.y & 0xFFFF0000u);
    b.x += __uint_as_float(u.z << 16);
    b.y += __uint_as_float(u.z & 0xFFFF0000u);
    b.z += __uint_as_float(u.w << 16);
    b.w += __uint_as_float(u.w & 0xFFFF0000u);
}

// Merged: sniff (local per block), node-histogram (1 edge/thread), cast x -> bf16 xb.
// cnt/sums pre-zeroed by hipMemsetAsync. Grid = 3125 (one thread per edge).
__global__ __launch_bounds__(256) void initcast_kernel(
    const void* __restrict__ x, const int* __restrict__ ei,
    int* __restrict__ flags, int* __restrict__ cnt,
    unsigned short* __restrict__ xb)
{
    __shared__ int cntF, cntI;
    int t = threadIdx.x;
    if (t == 0) { cntF = 0; cntI = 0; }
    __syncthreads();
    unsigned short wd = ((const unsigned short*)x)[2 * t];
    int e = (wd >> 7) & 0xFF;
    if (e >= 0x70 && e <= 0x8F) atomicAdd(&cntF, 1);        // bf16-plausible exponent
    if (t < 128 && ei[2 * t + 1] == 0) atomicAdd(&cntI, 1); // int64 high words are 0
    __syncthreads();
    int isf = (cntF < 128) ? 1 : 0;
    int i64 = (cntI > 64) ? 1 : 0;

    int gid = blockIdx.x * 256 + t;
    if (blockIdx.x == 0 && t == 0) {
        flags[0] = isf;
        flags[1] = i64;
    }

    // histogram: this thread's edge
    {
        int d = i64 ? ei[2 * N_EDGES + 2 * gid] : ei[N_EDGES + gid];
        atomicAdd(cnt + d, 1);
    }

    // cast: 8 elems/thread for gid < 400000
    int i = gid * 8;
    if (i < N_NODES * DD) {
        if (isf) {
            float4 a = *reinterpret_cast<const float4*>((const float*)x + i);
            float4 b = *reinterpret_cast<const float4*>((const float*)x + i + 4);
            ushort4 o0, o1;
            o0.x = __bfloat16_as_ushort(__float2bfloat16(a.x));
            o0.y = __bfloat16_as_ushort(__float2bfloat16(a.y));
            o0.z = __bfloat16_as_ushort(__float2bfloat16(a.z));
            o0.w = __bfloat16_as_ushort(__float2bfloat16(a.w));
            o1.x = __bfloat16_as_ushort(__float2bfloat16(b.x));
            o1.y = __bfloat16_as_ushort(__float2bfloat16(b.y));
            o1.z = __bfloat16_as_ushort(__float2bfloat16(b.z));
            o1.w = __bfloat16_as_ushort(__float2bfloat16(b.w));
            *reinterpret_cast<ushort4*>(xb + i) = o0;
            *reinterpret_cast<ushort4*>(xb + i + 4) = o1;
        } else {
            *reinterpret_cast<uint4*>(xb + i) =
                *reinterpret_cast<const uint4*>((const unsigned short*)x + i);
        }
    }
}

// block-local exclusive scan into off + per-block sums
__global__ __launch_bounds__(256) void scanA_kernel(const int* __restrict__ cnt,
                                                    int* __restrict__ off,
                                                    int* __restrict__ bsum) {
    __shared__ int tmp[256];
    int t = threadIdx.x;
    int i = blockIdx.x * 256 + t;
    int v = (i < N_NODES) ? cnt[i] : 0;
    tmp[t] = v;
    __syncthreads();
    #pragma unroll
    for (int d = 1; d < 256; d <<= 1) {
        int u = (t >= d) ? tmp[t - d] : 0;
        __syncthreads();
        tmp[t] += u;
        __syncthreads();
    }
    if (i < N_NODES) off[i] = tmp[t] - v;
    if (t == 255) bsum[blockIdx.x] = tmp[255];
}

// scanB folded in: every block redundantly scans bsum[196] in LDS, then adds its base.
// Also seeds bucket cursors (bcur, line-padded stride 16) and off[N_NODES].
__global__ __launch_bounds__(256) void scanC_kernel(const int* __restrict__ bsum,
                                                    int* __restrict__ off,
                                                    int* __restrict__ bcur) {
    __shared__ int tmp[256];
    int t = threadIdx.x;
    int v = (t < SCAN_BLOCKS) ? bsum[t] : 0;
    tmp[t] = v;
    __syncthreads();
    #pragma unroll
    for (int d = 1; d < 256; d <<= 1) {
        int u = (t >= d) ? tmp[t - d] : 0;
        __syncthreads();
        tmp[t] += u;
        __syncthreads();
    }
    int base = (blockIdx.x == 0) ? 0 : tmp[blockIdx.x - 1];
    int i = blockIdx.x * 256 + t;
    if (i < N_NODES) {
        int o = off[i] + base;
        off[i] = o;
        if ((i & 63) == 0) bcur[(i >> 6) * 16] = o;
    }
    if (blockIdx.x == SCAN_BLOCKS - 1 && t == 0) off[N_NODES] = tmp[SCAN_BLOCKS - 1];
}

// Pass A (R17): block-local LDS counting sort by bucket (bucket = dst>>6), then
// burst write each bucket's run into its reserved span of tmp32. One global
// atomic per (block,bucket) instead of one per edge; writes are coalesced runs
// (avg 5.2 entries) so each 64B line is produced by ~2-3 blocks, not ~8 XCDs.
// Pack: s(16) | (d&63)<<16 | bucket<<22 — bucket<782 fits 10 bits, never all-ones.
__global__ __launch_bounds__(1024) void fillA_kernel(const int* __restrict__ ei,
                                                     int* __restrict__ bcur,
                                                     unsigned int* __restrict__ tmp,
                                                     const int* __restrict__ flags) {
    __shared__ int sHist[1024];            // per-bucket count (782 used)
    __shared__ int sStart[1024];           // exclusive scan (local sorted offset)
    __shared__ int sCur[1024];             // scatter cursors
    __shared__ int sBase[1024];            // reserved global base per bucket
    __shared__ int sWS[16];                // per-wave scan sums
    __shared__ unsigned int sorted[FA2_EPB];

    int t = threadIdx.x;
    int lane = t & 63, wid = t >> 6;
    int i64 = flags[1];

    sHist[t] = 0;
    __syncthreads();

    unsigned int vals[4];
    int e0 = blockIdx.x * FA2_EPB + t;
    #pragma unroll
    for (int j = 0; j < 4; ++j) {
        int e = e0 + j * 1024;
        vals[j] = 0xFFFFFFFFu;
        if (e < N_EDGES) {
            int s, d;
            if (i64) { s = ei[2 * e]; d = ei[2 * N_EDGES + 2 * e]; }
            else     { s = ei[e];     d = ei[N_EDGES + e]; }
            int b = d >> 6;
            vals[j] = (unsigned)s | ((unsigned)(d & 63) << 16) | ((unsigned)b << 22);
            atomicAdd(&sHist[b], 1);
        }
    }
    __syncthreads();

    // inclusive scan of sHist[0..1023]: shfl within wave, then scan 16 wave sums
    int h = sHist[t];
    int x = h;
    #pragma unroll
    for (int dd = 1; dd < 64; dd <<= 1) {
        int y = __shfl_up(x, dd, 64);
        if (lane >= dd) x += y;
    }
    if (lane == 63) sWS[wid] = x;
    __syncthreads();
    if (wid == 0) {
        int v = (lane < 16) ? sWS[lane] : 0;
        #pragma unroll
        for (int dd = 1; dd < 16; dd <<= 1) {
            int y = __shfl_up(v, dd, 64);
            if (lane >= dd) v += y;
        }
        if (lane < 16) sWS[lane] = v;
    }
    __syncthreads();
    int base = (wid == 0) ? 0 : sWS[wid - 1];
    int incl = x + base;
    int lst = incl - h;
    sStart[t] = lst;
    sCur[t] = lst;
    if (t < NBUCKET && h > 0) sBase[t] = atomicAdd(bcur + t * 16, h);
    int total = sWS[15];
    __syncthreads();

    // LDS scatter: sort this block's edges by bucket
    #pragma unroll
    for (int j = 0; j < 4; ++j) {
        unsigned int v = vals[j];
        if (v != 0xFFFFFFFFu) {
            int b = v >> 22;
            int p = atomicAdd(&sCur[b], 1);
            sorted[p] = v;
        }
    }
    __syncthreads();

    // burst write-out: consecutive i in the same bucket -> consecutive global addrs
    for (int i = t; i < total; i += 1024) {
        unsigned int v = sorted[i];
        int b = v >> 22;
        tmp[sBase[b] + (i - sStart[b])] = v & 0x3FFFFFu;  // strip bucket bits for fillB
    }
}

// Pass B: one block per bucket; exact per-node placement via LDS counters.
__global__ __launch_bounds__(256) void fillB_kernel(const int* __restrict__ off,
                                                    const unsigned int* __restrict__ tmp,
                                                    unsigned short* __restrict__ srt) {
    __shared__ int cur64[64];
    int b = blockIdx.x;
    int t = threadIdx.x;
    if (t < 64) {
        int idx = b * 64 + t;
        cur64[t] = (idx < N_NODES) ? off[idx] : N_EDGES;
    }
    __syncthreads();
    int start = off[b * 64];
    int endn  = (b + 1) * 64; if (endn > N_NODES) endn = N_NODES;
    int end   = off[endn];
    for (int i = start + t; i < end; i += 256) {
        unsigned v = tmp[i];
        int pos = atomicAdd(&cur64[v >> 16], 1);
        srt[pos] = (unsigned short)(v & 0xFFFFu);
    }
}

// Fused: CSR bf16-gather -> LDS -> GEMM (W1,b1) -> hpre + BN sums.
// R13-proven local optimum: 512 threads = 8 waves x 8 row-slots; lane (rs = lane>>3,
// ch = lane&7) owns the FULL neighbor stream of row (w*8+rs), chunk ch.
// R23: block's srt segment staged in LDS as byte offsets (n<<7). R25/R26: out_
// stores nontemporal (hpre is stream-once; keep xb resident in L2).
// wcol[64] epilogue is the proven form (k-tiling detonates: R19/R21).
// DO NOT alter lane geometry or block shape (R24 regressed).
__global__ __launch_bounds__(512, 4) void gather_gemm_stats_kernel(
    const unsigned short* __restrict__ xb, const void* __restrict__ self_src, int force_f32,
    const int* __restrict__ off, const unsigned short* __restrict__ srt,
    const void* __restrict__ W, const void* __restrict__ bias,
    float* __restrict__ out_, float* __restrict__ sums, const int* __restrict__ flags)
{
    __shared__ float sIn[RPB][DD];            // 16 KB agg tile
    __shared__ float r1[8][DD], r2[8][DD];    // 4 KB stats
    __shared__ unsigned sOff[2048];           // 8 KB staged neighbor byte-offsets
    int tid = threadIdx.x;
    int lane = tid & 63, w = tid >> 6;        // wave 0..7
    int rs = lane >> 3, ch = lane & 7;
    int row0 = blockIdx.x * RPB;
    int isf = force_f32 ? 1 : flags[0];

    // cooperative stage: block's contiguous srt range -> LDS byte offsets.
    int rEnd = row0 + RPB; if (rEnd > N_NODES) rEnd = N_NODES;
    int blkStart = off[row0];
    int blkCount = off[rEnd] - blkStart;
    for (int i = tid; i < blkCount; i += 512)
        sOff[i] = ((unsigned)srt[blkStart + i]) << 7;
    __syncthreads();

    int lr = w * 8 + rs;
    int r = row0 + lr;
    float4 a  = make_float4(0.f, 0.f, 0.f, 0.f);
    float4 b  = make_float4(0.f, 0.f, 0.f, 0.f);
    float4 a2 = make_float4(0.f, 0.f, 0.f, 0.f);
    float4 b2 = make_float4(0.f, 0.f, 0.f, 0.f);
    if (r < N_NODES) {
        a = isf ? ld4<true>(self_src, r * DD + 8 * ch)
                : ld4<false>(self_src, r * DD + 8 * ch);
        b = isf ? ld4<true>(self_src, r * DD + 8 * ch + 4)
                : ld4<false>(self_src, r * DD + 8 * ch + 4);
        int k0 = off[r] - blkStart, k1 = off[r + 1] - blkStart;
        const char* xbc = (const char*)xb + 16 * ch;  // lane-constant chunk base
        int k = k0;
        for (; k + 16 <= k1; k += 16) {       // 16-deep pipelined neighbor loads
            unsigned o0  = sOff[k],      o1  = sOff[k + 1],  o2  = sOff[k + 2],  o3  = sOff[k + 3];
            unsigned o4  = sOff[k + 4],  o5  = sOff[k + 5],  o6  = sOff[k + 6],  o7  = sOff[k + 7];
            unsigned o8  = sOff[k + 8],  o9  = sOff[k + 9],  o10 = sOff[k + 10], o11 = sOff[k + 11];
            unsigned o12 = sOff[k + 12], o13 = sOff[k + 13], o14 = sOff[k + 14], o15 = sOff[k + 15];
            uint4 u0  = *reinterpret_cast<const uint4*>(xbc + o0);
            uint4 u1  = *reinterpret_cast<const uint4*>(xbc + o1);
            uint4 u2  = *reinterpret_cast<const uint4*>(xbc + o2);
            uint4 u3  = *reinterpret_cast<const uint4*>(xbc + o3);
            uint4 u4  = *reinterpret_cast<const uint4*>(xbc + o4);
            uint4 u5  = *reinterpret_cast<const uint4*>(xbc + o5);
            uint4 u6  = *reinterpret_cast<const uint4*>(xbc + o6);
            uint4 u7  = *reinterpret_cast<const uint4*>(xbc + o7);
            uint4 u8  = *reinterpret_cast<const uint4*>(xbc + o8);
            uint4 u9  = *reinterpret_cast<const uint4*>(xbc + o9);
            uint4 u10 = *reinterpret_cast<const uint4*>(xbc + o10);
            uint4 u11 = *reinterpret_cast<const uint4*>(xbc + o11);
            uint4 u12 = *reinterpret_cast<const uint4*>(xbc + o12);
            uint4 u13 = *reinterpret_cast<const uint4*>(xbc + o13);
            uint4 u14 = *reinterpret_cast<const uint4*>(xbc + o14);
            uint4 u15 = *reinterpret_cast<const uint4*>(xbc + o15);
            acc8(a, b, u0);   acc8(a2, b2, u1);
            acc8(a, b, u2);   acc8(a2, b2, u3);
            acc8(a, b, u4);   acc8(a2, b2, u5);
            acc8(a, b, u6);   acc8(a2, b2, u7);
            acc8(a, b, u8);   acc8(a2, b2, u9);
            acc8(a, b, u10);  acc8(a2, b2, u11);
            acc8(a, b, u12);  acc8(a2, b2, u13);
            acc8(a, b, u14);  acc8(a2, b2, u15);
        }
        for (; k + 8 <= k1; k += 8) {         // 8-deep tail
            unsigned o0 = sOff[k],     o1 = sOff[k + 1], o2 = sOff[k + 2], o3 = sOff[k + 3];
            unsigned o4 = sOff[k + 4], o5 = sOff[k + 5], o6 = sOff[k + 6], o7 = sOff[k + 7];
            uint4 u0 = *reinterpret_cast<const uint4*>(xbc + o0);
            uint4 u1 = *reinterpret_cast<const uint4*>(xbc + o1);
            uint4 u2 = *reinterpret_cast<const uint4*>(xbc + o2);
            uint4 u3 = *reinterpret_cast<const uint4*>(xbc + o3);
            uint4 u4 = *reinterpret_cast<const uint4*>(xbc + o4);
            uint4 u5 = *reinterpret_cast<const uint4*>(xbc + o5);
            uint4 u6 = *reinterpret_cast<const uint4*>(xbc + o6);
            uint4 u7 = *reinterpret_cast<const uint4*>(xbc + o7);
            acc8(a, b, u0);
            acc8(a2, b2, u1);
            acc8(a, b, u2);
            acc8(a2, b2, u3);
            acc8(a, b, u4);
            acc8(a2, b2, u5);
            acc8(a, b, u6);
            acc8(a2, b2, u7);
        }
        for (; k + 2 <= k1; k += 2) {
            unsigned o0 = sOff[k], o1 = sOff[k + 1];
            uint4 u0 = *reinterpret_cast<const uint4*>(xbc + o0);
            uint4 u1 = *reinterpret_cast<const uint4*>(xbc + o1);
            acc8(a, b, u0);
            acc8(a2, b2, u1);
        }
        if (k < k1) {
            acc8(a, b, *reinterpret_cast<const uint4*>(xbc + sOff[k]));
        }
        a.x += a2.x; a.y += a2.y; a.z += a2.z; a.w += a2.w;
        b.x += b2.x; b.y += b2.y; b.z += b2.z; b.w += b2.w;
    }
    *reinterpret_cast<float4*>(&sIn[lr][8 * ch]) = a;
    *reinterpret_cast<float4*>(&sIn[lr][8 * ch + 4]) = b;
    __syncthreads();

    float wcol[DD];                           // W[:,c], c = lane
    #pragma unroll
    for (int k = 0; k < DD; ++k) wcol[k] = loadF(W, k * DD + lane, isf);
    float bv = loadF(bias, lane, isf);

    float s1 = 0.f, s2 = 0.f;
    #pragma unroll 4
    for (int j = 0; j < 8; ++j) {
        int jr = w * 8 + j;
        float c0 = 0.f, c1 = 0.f, c2 = 0.f, c3 = 0.f;
        #pragma unroll
        for (int k = 0; k < DD; k += 4) {
            float4 aa = *reinterpret_cast<const float4*>(&sIn[jr][k]);  // wave-uniform broadcast
            c0 += aa.x * wcol[k];
            c1 += aa.y * wcol[k + 1];
            c2 += aa.z * wcol[k + 2];
            c3 += aa.w * wcol[k + 3];
        }
        float acc = bv + ((c0 + c1) + (c2 + c3));
        int rr = row0 + jr;
        if (rr < N_NODES) {
            __builtin_nontemporal_store(acc, &out_[rr * DD + lane]);  // R25: stream-once
            s1 += acc;
            s2 += acc * acc;
        }
    }
    r1[w][lane] = s1; r2[w][lane] = s2;
    __syncthreads();
    if (w == 0) {
        float t1 = 0.f, t2 = 0.f;
        #pragma unroll
        for (int q = 0; q < 8; ++q) { t1 += r1[q][lane]; t2 += r2[q][lane]; }
        atomicAdd(&sums[lane], t1);
        atomicAdd(&sums[64 + lane], t2);
    }
}

// h = relu(hpre*scale+shift); out = relu(h @ W2 + b2) -> fp32 (+ optional bf16 shadow).
// BN scale/shift computed inline from sums. In-place safe (LDS staged).
// wcol[64] form — proven; k-tiling detonates the allocator (R21).
// R25/R26: in_ loads + oF/obf stores nontemporal (stream-once; keep xb in L2
// for the following gather). nt load via native ext_vector_type.
__global__ __launch_bounds__(256) void mlp2_kernel(
    const float* __restrict__ in_, const float* __restrict__ sums,
    const void* __restrict__ gma, const void* __restrict__ beta,
    const void* __restrict__ W, const void* __restrict__ bias,
    float* __restrict__ oF, unsigned short* obf, const int* __restrict__ flags)
{
    __shared__ float sIn[64][DD];
    __shared__ float sScale[DD], sShift[DD];
    int isf = flags[0];
    int tid = threadIdx.x;
    int c = tid & 63, g = tid >> 6;
    int row0 = blockIdx.x * 64;

    if (tid < 64) {
        float S1 = sums[tid];
        float S2 = sums[64 + tid];
        float mean = S1 * (1.0f / N_NODES);
        float var  = S2 * (1.0f / N_NODES) - mean * mean;
        float scale = rsqrtf(var + BN_EPS) * loadF(gma, tid, isf);
        sScale[tid] = scale;
        sShift[tid] = loadF(beta, tid, isf) - mean * scale;
    }
    __syncthreads();

    #pragma unroll
    for (int j = 0; j < 4; ++j) {
        int lr = (tid >> 4) + 16 * j;
        int cc = (tid & 15) << 2;
        int r = row0 + lr;
        float4 v = make_float4(0.f, 0.f, 0.f, 0.f);
        if (r < N_NODES) {
            nt4 nv = __builtin_nontemporal_load(
                         reinterpret_cast<const nt4*>(in_ + r * DD + cc));  // R26
            v = make_float4(nv.x, nv.y, nv.z, nv.w);
            float4 sc = *reinterpret_cast<const float4*>(&sScale[cc]);
            float4 sh = *reinterpret_cast<const float4*>(&sShift[cc]);
            v.x = fmaxf(v.x * sc.x + sh.x, 0.f);
            v.y = fmaxf(v.y * sc.y + sh.y, 0.f);
            v.z = fmaxf(v.z * sc.z + sh.z, 0.f);
            v.w = fmaxf(v.w * sc.w + sh.w, 0.f);
        }
        *reinterpret_cast<float4*>(&sIn[lr][cc]) = v;
    }
    __syncthreads();

    float wcol[DD];
    #pragma unroll
    for (int k = 0; k < DD; ++k) wcol[k] = loadF(W, k * DD + c, isf);
    float bv = loadF(bias, c, isf);

    #pragma unroll 4
    for (int j = 0; j < 16; ++j) {
        int lr = g * 16 + j;
        float a0 = 0.f, a1 = 0.f, a2 = 0.f, a3 = 0.f;
        #pragma unroll
        for (int k = 0; k < DD; k += 4) {
            float4 a = *reinterpret_cast<const float4*>(&sIn[lr][k]);
            a0 += a.x * wcol[k];
            a1 += a.y * wcol[k + 1];
            a2 += a.z * wcol[k + 2];
            a3 += a.w * wcol[k + 3];
        }
        float acc = fmaxf(bv + ((a0 + a1) + (a2 + a3)), 0.f);
        int r = row0 + lr;
        if (r < N_NODES) {
            __builtin_nontemporal_store(acc, &oF[r * DD + c]);           // R25
            if (obf) {
                unsigned short h = __bfloat16_as_ushort(__float2bfloat16(acc));
                __builtin_nontemporal_store(h, &obf[r * DD + c]);        // R25
            }
        }
    }
}

extern "C" void kernel_launch(void* const* d_in, const int* in_sizes, int n_in,
                              void* d_out, int out_size, void* d_ws, size_t ws_size,
                              hipStream_t stream)
{
    (void)in_sizes; (void)n_in; (void)out_size; (void)ws_size;
    const void* x  = d_in[0];
    const int* ei  = (const int*)d_in[1];
    const void* W1_0 = d_in[2];  const void* b1_0 = d_in[3];
    const void* g_0  = d_in[4];  const void* be_0 = d_in[5];
    const void* W2_0 = d_in[6];  const void* b2_0 = d_in[7];
    const void* W1_1 = d_in[8];  const void* b1_1 = d_in[9];
    const void* g_1  = d_in[10]; const void* be_1 = d_in[11];
    const void* W2_1 = d_in[12]; const void* b2_1 = d_in[13];

    float* wsf   = (float*)d_ws;
    float* sumsA = wsf;                            // 128
    float* sumsB = wsf + 128;                      // 128
    int*  flags  = (int*)(wsf + 256);              // 2
    int*  cnt    = (int*)(wsf + 512);              // 50048
    int*  off    = cnt + 50048;                    // 50064
    int*  bcur   = off + 50064;                    // 782*16 = 12512 (line-padded)
    int*  bsum   = bcur + 12512;                   // 256
    unsigned int* tmp32 = (unsigned int*)(bsum + 256) + 48;   // 800000 u32
    unsigned short* srt = (unsigned short*)(tmp32 + 800000);  // 800000 u16
    unsigned short* xb  = srt + 800064;                       // 3.2M bf16, 16B-aligned
    float* O1    = (float*)d_out;                  // h1 (fp32 self-term source)
    float* O2    = O1 + (size_t)N_NODES * DD;      // hpre scratch -> h2

    dim3 blk(256);

    // zero sums/flags/cnt, then CSR build (hist folded into initcast) + bf16 shadow
    hipMemsetAsync(d_ws, 0, (size_t)(512 + 50048) * 4, stream);
    initcast_kernel<<<EDGE_BLOCKS, blk, 0, stream>>>(x, ei, flags, cnt, xb);
    scanA_kernel<<<SCAN_BLOCKS, blk, 0, stream>>>(cnt, off, bsum);
    scanC_kernel<<<SCAN_BLOCKS, blk, 0, stream>>>(bsum, off, bcur);
    fillA_kernel<<<FA2_BLOCKS, 1024, 0, stream>>>(ei, bcur, tmp32, flags);
    fillB_kernel<<<NBUCKET, blk, 0, stream>>>(off, tmp32, srt);

    // ---- layer 1 ----
    gather_gemm_stats_kernel<<<GBLOCKS, 512, 0, stream>>>(xb, x, 0, off, srt, W1_0, b1_0,
                                                          O2, sumsA, flags);
    mlp2_kernel<<<MBLOCKS, blk, 0, stream>>>(O2, sumsA, g_0, be_0, W2_0, b2_0, O1, xb, flags);

    // ---- layer 2 ----
    gather_gemm_stats_kernel<<<GBLOCKS, 512, 0, stream>>>(xb, O1, 1, off, srt, W1_1, b1_1,
                                                          O2, sumsB, flags);
    mlp2_kernel<<<MBLOCKS, blk, 0, stream>>>(O2, sumsB, g_1, be_1, W2_1, b2_1, O2, nullptr, flags);
}